// Round 7
// baseline (3172.640 us; speedup 1.0000x reference)
//
#include <hip/hip_runtime.h>
#include <stdint.h>

#define S_DET 725
#define S_ANG 360
#define OUTD  512
#define NB    4

typedef float    float4v __attribute__((ext_vector_type(4)));
typedef int      int4v   __attribute__((ext_vector_type(4)));
typedef _Float16 half8   __attribute__((ext_vector_type(8)));
typedef _Float16 half4   __attribute__((ext_vector_type(4)));
typedef _Float16 half2v  __attribute__((ext_vector_type(2)));

#define GAS __attribute__((address_space(1)))
#define LAS __attribute__((address_space(3)))

// async global->LDS, 16B per lane, LDS dst wave-uniform (lane i writes dst+16*i)
__device__ __forceinline__ void async16(const void* src, void* lds) {
  __builtin_amdgcn_global_load_lds((const GAS void*)(uintptr_t)src,
                                   (LAS void*)(uint32_t)(uintptr_t)lds, 16, 0, 0);
}

// ---------------------------------------------------------------------------
// Weight prep: fold BN into weights/bias, cast f16. mid-conv layout for the
// K-HALF-RESIDENT scheme: halfs index = l*102400 + h*51200 + t*2048 + g*512
// + n*8 + e, where k = h*32 + g*8 + e (input ch), n = out ch. In-kernel the
// h-half is a linear 102400B block; wf reads are quarter-wave-contiguous.
// Tail: w6 [t*64+k]; conv1 A-fragments (K=25 taps padded to 32).
// ---------------------------------------------------------------------------
__global__ __launch_bounds__(256)
void prep_weights(const float* __restrict__ wsin, const float* __restrict__ sg,
                  const float* __restrict__ sb,  const float* __restrict__ sm,
                  const float* __restrict__ sv,
                  const float* __restrict__ wct, const float* __restrict__ cg,
                  const float* __restrict__ cbt, const float* __restrict__ cm,
                  const float* __restrict__ cv,
                  const float* __restrict__ wsin6, const float* __restrict__ wct6,
                  const float* __restrict__ wsin1, const float* __restrict__ wct1,
                  _Float16* __restrict__ wout, float* __restrict__ bout,
                  _Float16* __restrict__ w6out, _Float16* __restrict__ w1fout)
{
  int id = blockIdx.x * 256 + threadIdx.x;
  if (id < 9 * 102400) {
    int l   = id / 102400;          // layer 0..8 (0-3 sinogram, 4-8 image)
    int rem = id - l * 102400;      // t*4096 + k*64 + n  (source [5][5][64][64])
    int t = rem >> 12;
    int kn = rem & 4095;
    int k = kn >> 6, n = kn & 63;
    const float *w, *g, *b, *m, *v;
    if (l < 4) { w = wsin + l*102400; g = sg + l*64; b = sb + l*64; m = sm + l*64; v = sv + l*64; }
    else { int li = l - 4; w = wct + li*102400; g = cg + li*64; b = cbt + li*64; m = cm + li*64; v = cv + li*64; }
    float s = g[n] * rsqrtf(v[n] + 1e-3f);
    float val = w[rem] * s;
    int h = k >> 5, gc = (k >> 3) & 3, e = k & 7;
    wout[(size_t)l*102400 + h*51200 + t*2048 + gc*512 + n*8 + e] = (_Float16)val;
    if (rem < 64)  // t==0,k==0 -> n==rem
      bout[l*64 + rem] = b[rem] - m[rem] * s;
  } else {
    int r = id - 9 * 102400;
    if (r < 3200) {  // [0,1600) sino w6, [1600,3200) ct w6; layout [t*64+k]
      w6out[r] = (_Float16)(r < 1600 ? wsin6[r] : wct6[r - 1600]);
    } else if (r < 3200 + 4096) {
      // conv1 A-fragments: q = layer*2048 + ci*512 + ln*8 + e
      int q = r - 3200;
      int layer = q >> 11;
      int idx = q & 2047;
      int ci = idx >> 9, ln = (idx >> 3) & 63, e = idx & 7;
      int ch = ci * 16 + (ln & 15);
      int k = (ln >> 4) * 8 + e;          // tap index (pad >=25 -> 0)
      float val = 0.f;
      if (k < 25) val = (layer ? wct1 : wsin1)[k * 64 + ch];
      w1fout[q] = (_Float16)val;
    }
  }
}

// ---------------------------------------------------------------------------
// First conv 1->64 via MFMA im2col (unchanged from R6).
// ---------------------------------------------------------------------------
template <int IMG>
__global__ __launch_bounds__(256)
void conv1_mfma(const float* __restrict__ src, _Float16* __restrict__ dst,
                const _Float16* __restrict__ w1f, const float* __restrict__ b1,
                int H, int W, int b0)
{
  __shared__ __align__(16) float rawt[400];
  __shared__ __align__(16) char imc[256 * 80];
  const int tid = threadIdx.x;
  const int wv = tid >> 6, ln = tid & 63;
  const int bz = blockIdx.z, gb = b0 + bz;
  const int y0 = blockIdx.y * 16, x0 = blockIdx.x * 16;
  for (int i = tid; i < 400; i += 256) {
    int iy = i / 20, ix = i - iy * 20;
    int y = y0 - 2 + iy, x = x0 - 2 + ix;
    float v = 0.f;
    if (y >= 0 && y < H && x >= 0 && x < W) {
      if (IMG) v = 4.f * src[(size_t)(y * W + x) * 4 + gb];
      else     v = src[((size_t)gb * H + y) * W + x];
    }
    rawt[i] = v;
  }
  __syncthreads();
  {
    const int ty = tid >> 4, tx = tid & 15;
    _Float16 row[32];
    int dy = 0, dx = 0;
#pragma unroll
    for (int t = 0; t < 25; ++t) {
      row[t] = (_Float16)rawt[(ty + dy) * 20 + tx + dx];
      if (++dx == 5) { dx = 0; ++dy; }
    }
#pragma unroll
    for (int t = 25; t < 32; ++t) row[t] = (_Float16)0.f;
    char* dp = imc + tid * 80;
#pragma unroll
    for (int j = 0; j < 4; ++j)
      *(half8*)(dp + j * 16) = *(const half8*)((const char*)row + j * 16);
  }
  __syncthreads();

  half8 wf[4];
#pragma unroll
  for (int ci = 0; ci < 4; ++ci) wf[ci] = ((const half8*)w1f)[ci * 64 + ln];

  float4v acc[4][4];
#pragma unroll
  for (int pi = 0; pi < 4; ++pi)
#pragma unroll
    for (int ci = 0; ci < 4; ++ci) acc[pi][ci] = (float4v){0.f, 0.f, 0.f, 0.f};

#pragma unroll
  for (int pi = 0; pi < 4; ++pi) {
    const int px = (wv * 4 + pi) * 16 + (ln & 15);
    half8 af = *(const half8*)(imc + px * 80 + ((ln >> 4) << 4));
#pragma unroll
    for (int ci = 0; ci < 4; ++ci)
      acc[pi][ci] = __builtin_amdgcn_mfma_f32_16x16x32_f16(wf[ci], af, acc[pi][ci], 0, 0, 0);
  }

  const int tx = ln & 15;
  const int x = x0 + tx;
#pragma unroll
  for (int pi = 0; pi < 4; ++pi) {
    const int y = y0 + wv * 4 + pi;
    if (y < H && x < W) {
      _Float16* dp = dst + ((size_t)(bz * H + y) * W + x) * 64;
#pragma unroll
      for (int ci = 0; ci < 4; ++ci) {
        const int cbase = ci * 16 + (ln >> 4) * 4;
        const float4v bv = *(const float4v*)(b1 + cbase);
        half4 h;
#pragma unroll
        for (int r = 0; r < 4; ++r) {
          float v = acc[pi][ci][r] + bv[r];
          v = v > 0.f ? v : 0.f;
          h[r] = (_Float16)v;
        }
        *(half4*)(dp + cbase) = h;
      }
    }
  }
}

// ---------------------------------------------------------------------------
// Residual conv 64->64 + BN bias + relu + fused fc — K-HALF-RESIDENT scheme.
// 512 threads, 16 rows x 32 cols output tile. For each K-half h (in-ch 32):
// stage pixel half-tile (20x36 px x 64B, [g][px] blocked => conflict-free,
// 64B-line-aligned fetches) + ALL 25 taps' half-weights (102.4KB) + w6 in
// LDS, then a barrier-free vmcnt-free 25-tap loop: 9 ds_read_b128 + 20 MFMA
// per wave-tap. 2 barriers per half instead of 25 per layer.
// ---------------------------------------------------------------------------
__global__ __launch_bounds__(512, 2)
void mid_conv(const _Float16* __restrict__ src, _Float16* __restrict__ dst,
              float* __restrict__ accum,
              const _Float16* __restrict__ wt, const _Float16* __restrict__ w6g,
              const float* __restrict__ bias, const char* __restrict__ zbuf,
              int H, int W, int b0)
{
  __shared__ __align__(16) char smem[46080 + 102400 + 3200 + 16];
  char* const atile = smem;                 // [g(4)][px(720)] 16B units
  char* const wlds  = smem + 46080;         // [t(25)][g(4)][n(64)] 16B units
  _Float16* const w6l = (_Float16*)(smem + 148480);  // 1600 halfs [t*64+k]
  char* const zsl = smem + 151680;          // 16B zeros
  const int tid = threadIdx.x;
  const int wv = tid >> 6, ln = tid & 63;
  const int bz = blockIdx.z, gb = b0 + bz;
  const int y0 = blockIdx.y * 16, x0 = blockIdx.x * 32;

  if (tid < 200) ((half8*)w6l)[tid] = ((const half8*)w6g)[tid];
  if (tid < 4) ((int*)zsl)[tid] = 0;

  float4v acc[4][4];
  float4v acc6[4];
#pragma unroll
  for (int pi = 0; pi < 4; ++pi) {
    acc6[pi] = (float4v){0.f, 0.f, 0.f, 0.f};
#pragma unroll
    for (int ci = 0; ci < 4; ++ci) acc[pi][ci] = (float4v){0.f, 0.f, 0.f, 0.f};
  }

  for (int h = 0; h < 2; ++h) {
    if (h) __syncthreads();   // protect LDS while other waves finish half 0
    // pixel half-tile: 720 px x 4 chunks = 2880 slots = 45 insts
    for (int inst = wv; inst < 45; inst += 8) {
      const int s = inst * 64 + ln;
      const int g = s / 720;
      const int px = s - g * 720;
      const int iy = px / 36, ix = px - iy * 36;
      const int y = y0 - 2 + iy, x = x0 - 2 + ix;
      const char* sp = (y >= 0 && y < H && x >= 0 && x < W)
          ? (const char*)(src + ((size_t)(bz * H + y) * W + x) * 64) + (h * 4 + g) * 16
          : zbuf + g * 16;
      async16(sp, atile + inst * 1024);
    }
    // half-weights: linear 102400B copy = 100 insts
    const char* wsrc = (const char*)wt + h * 102400;
    for (int inst = wv; inst < 100; inst += 8)
      async16(wsrc + inst * 1024 + ln * 16, wlds + inst * 1024);
    __syncthreads();

    int dy = 0, dx = 0;
    const int gq = ln >> 4;
    for (int t = 0; t < 25; ++t) {
      half8 wf[4], af[4], wf6;
#pragma unroll
      for (int ci = 0; ci < 4; ++ci)
        wf[ci] = *(const half8*)(wlds + t * 4096 + gq * 1024 + (ci * 16 + (ln & 15)) * 16);
      wf6 = *(const half8*)(((ln & 15) == 0)
              ? (const char*)w6l + t * 128 + h * 64 + gq * 16
              : zsl);
#pragma unroll
      for (int pi = 0; pi < 4; ++pi) {
        const int px = (wv * 2 + (pi >> 1) + dy) * 36 + (pi & 1) * 16 + (ln & 15) + dx;
        af[pi] = *(const half8*)(atile + gq * 11520 + px * 16);
      }
#pragma unroll
      for (int pi = 0; pi < 4; ++pi) {
#pragma unroll
        for (int ci = 0; ci < 4; ++ci)
          acc[pi][ci] = __builtin_amdgcn_mfma_f32_16x16x32_f16(
              wf[ci], af[pi], acc[pi][ci], 0, 0, 0);
        acc6[pi] = __builtin_amdgcn_mfma_f32_16x16x32_f16(
            wf6, af[pi], acc6[pi], 0, 0, 0);
      }
      if (++dx == 5) { dx = 0; ++dy; }
    }
  }

  // epilogue: D[m=ch][n=px]; lane holds 4 consecutive channels of 1 pixel
  const int tx = ln & 15;
#pragma unroll
  for (int pi = 0; pi < 4; ++pi) {
    const int y = y0 + wv * 2 + (pi >> 1);
    const int x = x0 + (pi & 1) * 16 + tx;
    if (y < H && x < W) {
      _Float16* dp = dst + ((size_t)(bz * H + y) * W + x) * 64;
#pragma unroll
      for (int ci = 0; ci < 4; ++ci) {
        const int cbase = ci * 16 + (ln >> 4) * 4;
        const float4v bv = *(const float4v*)(bias + cbase);
        half4 hh;
#pragma unroll
        for (int r = 0; r < 4; ++r) {
          float v = acc[pi][ci][r] + bv[r];
          v = v > 0.f ? v : 0.f;
          hh[r] = (_Float16)v;
        }
        *(half4*)(dp + cbase) = hh;
      }
    }
  }
  // fused fc of the input map: D row m=0 lives in lanes 0..15, reg 0
  if (ln < 16) {
#pragma unroll
    for (int pi = 0; pi < 4; ++pi) {
      const int y = y0 + wv * 2 + (pi >> 1);
      const int x2 = x0 + (pi & 1) * 16 + ln;
      if (y < H && x2 < W)
        accum[((size_t)gb * H + y) * W + x2] += acc6[pi][0];
    }
  }
}

// ---------------------------------------------------------------------------
// 64->1 conv of the LAST activation map (unchanged from R6).
// ---------------------------------------------------------------------------
__global__ __launch_bounds__(256, 3)
void fc_mfma(const _Float16* __restrict__ src, float* __restrict__ accum,
             const _Float16* __restrict__ w6g, const char* __restrict__ zbuf,
             int H, int W, int b0)
{
  __shared__ __align__(16) char atile[51200];
  const int tid = threadIdx.x;
  const int wv = tid >> 6, ln = tid & 63;
  const int bz = blockIdx.z, gb = b0 + bz;
  const int y0 = blockIdx.y * 16, x0 = blockIdx.x * 16;
  for (int inst = wv; inst < 50; inst += 4) {
    const int slot = inst * 64 + ln;
    const int p = slot >> 3, gp = slot & 7;
    const int g = gp ^ (p & 7);
    const int iy = p / 20, ix = p - iy * 20;
    const int y = y0 - 2 + iy, x = x0 - 2 + ix;
    const char* sp = (y >= 0 && y < H && x >= 0 && x < W)
        ? (const char*)(src + ((size_t)(bz * H + y) * W + x) * 64) + g * 16
        : zbuf + g * 16;
    async16(sp, atile + inst * 1024);
  }
  __syncthreads();

  float4v acc6[4];
#pragma unroll
  for (int pi = 0; pi < 4; ++pi) acc6[pi] = (float4v){0.f, 0.f, 0.f, 0.f};

  int dy = 0, dx = 0;
  for (int t = 0; t < 25; ++t) {
#pragma unroll
    for (int kc = 0; kc < 2; ++kc) {
      const int g0 = kc * 4 + (ln >> 4);
      half8 wf6 = {(_Float16)0, (_Float16)0, (_Float16)0, (_Float16)0,
                   (_Float16)0, (_Float16)0, (_Float16)0, (_Float16)0};
      if ((ln & 15) == 0)
        wf6 = *(const half8*)(w6g + t * 64 + kc * 32 + ((ln >> 4) << 3));
#pragma unroll
      for (int pi = 0; pi < 4; ++pi) {
        const int p = (wv * 4 + pi + dy) * 20 + (ln & 15) + dx;
        half8 af = *(const half8*)(atile + p * 128 + ((g0 ^ (p & 7)) << 4));
        acc6[pi] = __builtin_amdgcn_mfma_f32_16x16x32_f16(wf6, af, acc6[pi], 0, 0, 0);
      }
    }
    if (++dx == 5) { dx = 0; ++dy; }
  }
  if (ln < 16) {
#pragma unroll
    for (int pi = 0; pi < 4; ++pi) {
      const int y = y0 + wv * 4 + pi, x2 = x0 + ln;
      if (y < H && x2 < W)
        accum[((size_t)gb * H + y) * W + x2] += acc6[pi][0];
    }
  }
}

// ---------------------------------------------------------------------------
__global__ __launch_bounds__(256)
void write_desin(const float* __restrict__ accf, const float* __restrict__ inputs,
                 const float* __restrict__ b6, float* __restrict__ out)
{
  int id = blockIdx.x * 256 + threadIdx.x;
  if (id < NB * S_DET * S_ANG) out[id] = accf[id] * 0.25f + b6[0] + inputs[id];
}

// ---------------------------------------------------------------------------
__global__ __launch_bounds__(128)
void ramp_filter(const float* __restrict__ desin, const float* __restrict__ wb,
                 _Float16* __restrict__ f2h)
{
  __shared__ float col[1472];   // zero-padded: data at [368, 368+725)
  __shared__ float wl[725];
  const int blk = blockIdx.x;
  const int b = blk / 360, a = blk - b * 360;
  const int tid = threadIdx.x;
  for (int i = tid; i < 1472; i += 128) col[i] = 0.f;
  for (int i = tid; i < 725; i += 128) wl[i] = wb[i];
  __syncthreads();
  for (int i = tid; i < 725; i += 128) col[368 + i] = desin[(b * 725 + i) * 360 + a];
  __syncthreads();
  const int s0 = tid * 6;
  if (s0 < 725) {
    float o0 = 0, o1 = 0, o2 = 0, o3 = 0, o4 = 0, o5 = 0;
    const float* cb = col + 6 + s0;  // cb[t+j] = x[s0+j + t - 362]
    float r0 = cb[0], r1 = cb[1], r2 = cb[2], r3 = cb[3], r4 = cb[4], r5 = cb[5];
    for (int t = 0; t < 725; ++t) {
      float w = wl[t];
      o0 += r0 * w; o1 += r1 * w; o2 += r2 * w;
      o3 += r3 * w; o4 += r4 * w; o5 += r5 * w;
      r0 = r1; r1 = r2; r2 = r3; r3 = r4; r4 = r5; r5 = cb[t + 6];
    }
    float o[6] = { o0, o1, o2, o3, o4, o5 };
#pragma unroll
    for (int j = 0; j < 6; ++j)
      if (s0 + j < 725) f2h[((size_t)a * 725 + s0 + j) * 4 + b] = (_Float16)o[j];
  }
}

// ---------------------------------------------------------------------------
// Sparse backprojection: 32 nnz/thread (1024 blocks = 16 waves/CU), boundary
// atomics + interior plain stores, NT loads on the streams.
// ---------------------------------------------------------------------------
__global__ __launch_bounds__(256)
void backproj(const float* __restrict__ vals, const int* __restrict__ rows,
              const int* __restrict__ cols, const _Float16* __restrict__ f2h,
              float* __restrict__ rf)
{
  const int tid = blockIdx.x * 256 + threadIdx.x;   // 262144 threads
  const size_t i0 = (size_t)tid * 32;
  const int4v* rp = (const int4v*)(rows + i0);
  const int4v* cp = (const int4v*)(cols + i0);
  const float4v* vp = (const float4v*)(vals + i0);
  float a0 = 0, a1 = 0, a2 = 0, a3 = 0;
  int4v r0v = __builtin_nontemporal_load(rp);
  int cur = r0v[0];
  bool first = true;
#pragma unroll 4
  for (int q = 0; q < 8; ++q) {
    int4v r4 = (q == 0) ? r0v : __builtin_nontemporal_load(rp + q);
    int4v c4 = __builtin_nontemporal_load(cp + q);
    float4v v4 = __builtin_nontemporal_load(vp + q);
#pragma unroll
    for (int u = 0; u < 4; ++u) {
      int r = r4[u]; int c = c4[u]; float v = v4[u];
      if (r != cur) {
        float* p = rf + (size_t)cur * 4;
        if (first) {
          atomicAdd(p + 0, a0); atomicAdd(p + 1, a1);
          atomicAdd(p + 2, a2); atomicAdd(p + 3, a3);
          first = false;
        } else {
          p[0] = a0; p[1] = a1; p[2] = a2; p[3] = a3;
        }
        a0 = a1 = a2 = a3 = 0; cur = r;
      }
      const half4 f = *(const half4*)(f2h + (size_t)c * 4);
      a0 += v * (float)f[0]; a1 += v * (float)f[1];
      a2 += v * (float)f[2]; a3 += v * (float)f[3];
    }
  }
  float* p = rf + (size_t)cur * 4;
  atomicAdd(p + 0, a0); atomicAdd(p + 1, a1);
  atomicAdd(p + 2, a2); atomicAdd(p + 3, a3);
}

__global__ __launch_bounds__(256)
void write_fbp(const float* __restrict__ rf, float* __restrict__ out)
{
  int id = blockIdx.x * 256 + threadIdx.x;  // 4*262144 exact
  int b = id >> 18, p = id & 262143;
  out[id] = 4.f * rf[(size_t)p * 4 + b];
}

__global__ __launch_bounds__(256)
void write_outputs(const float* __restrict__ accf, const float* __restrict__ rf,
                   const float* __restrict__ b6, float* __restrict__ out)
{
  int id = blockIdx.x * 256 + threadIdx.x;  // 4*262144 exact
  int b = id >> 18, p = id & 262143;
  out[id] = accf[id] * 0.2f + b6[0] + 4.f * rf[(size_t)p * 4 + b];
}

// ---------------------------------------------------------------------------
extern "C" void kernel_launch(void* const* d_in, const int* in_sizes, int n_in,
                              void* d_out, int out_size, void* d_ws, size_t ws_size,
                              hipStream_t stream)
{
  (void)in_sizes; (void)n_in; (void)out_size;
  const float* inputs   = (const float*)d_in[0];
  const float* w_sin1   = (const float*)d_in[1];
  const float* b_sin1   = (const float*)d_in[2];
  const float* w_sin_mid= (const float*)d_in[3];
  const float* sin_gamma= (const float*)d_in[4];
  const float* sin_beta = (const float*)d_in[5];
  const float* sin_mean = (const float*)d_in[6];
  const float* sin_var  = (const float*)d_in[7];
  const float* w_sin6   = (const float*)d_in[8];
  const float* b_sin6   = (const float*)d_in[9];
  const float* w_ct1    = (const float*)d_in[10];
  const float* b_ct1    = (const float*)d_in[11];
  const float* w_ct_mid = (const float*)d_in[12];
  const float* ct_gamma = (const float*)d_in[13];
  const float* ct_beta  = (const float*)d_in[14];
  const float* ct_mean  = (const float*)d_in[15];
  const float* ct_var   = (const float*)d_in[16];
  const float* w_ct6    = (const float*)d_in[17];
  const float* b_ct6    = (const float*)d_in[18];
  const float* w_b      = (const float*)d_in[19];
  const float* at_vals  = (const float*)d_in[20];
  const int*   at_rows  = (const int*)d_in[21];
  const int*   at_cols  = (const int*)d_in[22];
  float* out = (float*)d_out;

  // adaptive batching: fixed tables ~11 MB; activations 2 x nbat x 33.55 MB.
  const size_t base = (size_t)11 << 20;
  const size_t act_per_batch = (size_t)2 * 262144 * 128;  // both ping-pong bufs
  int nbat = 1;
  if (ws_size >= base + 4 * act_per_batch) nbat = 4;
  else if (ws_size >= base + 2 * act_per_batch) nbat = 2;
  const int npass = 4 / nbat;

  char* ws = (char*)d_ws;
  size_t off = 0;
  auto alloc = [&](size_t bytes) {
    char* p = ws + off;
    off = (off + bytes + 255) & ~(size_t)255;
    return p;
  };
  char*     zbuf    = alloc(256);
  _Float16* wmid    = (_Float16*)alloc((size_t)9 * 102400 * 2);
  float*    biasmid = (float*)alloc(9 * 64 * 4);
  _Float16* w6s     = (_Float16*)alloc(3200 * 2);
  _Float16* w1f     = (_Float16*)alloc(4096 * 2);
  float*    rf      = (float*)alloc((size_t)262144 * 16);
  char*     shreg   = alloc((size_t)262144 * 16);  // f2h (2.1MB) / acc_fc (4.18MB) union
  _Float16* act_a   = (_Float16*)alloc((size_t)nbat * 262144 * 128);
  _Float16* act_b   = (_Float16*)alloc((size_t)nbat * 262144 * 128);
  _Float16* f2h    = (_Float16*)shreg;
  float*    acc_fc = (float*)shreg;

  hipMemsetAsync(zbuf, 0, 256, stream);
  hipMemsetAsync(rf, 0, (size_t)262144 * 16, stream);
  hipMemsetAsync(acc_fc, 0, (size_t)262144 * 16, stream);

  prep_weights<<<3630, 256, 0, stream>>>(w_sin_mid, sin_gamma, sin_beta, sin_mean, sin_var,
                                         w_ct_mid, ct_gamma, ct_beta, ct_mean, ct_var,
                                         w_sin6, w_ct6, w_sin1, w_ct1,
                                         wmid, biasmid, w6s, w1f);

  // ---- sinogram CNN (H=725, W=360) ----
  for (int p = 0; p < npass; ++p) {
    const int b0 = p * nbat;
    conv1_mfma<0><<<dim3(23, 46, nbat), 256, 0, stream>>>(inputs, act_a, w1f, b_sin1,
                                                          725, 360, b0);
    _Float16* cur = act_a; _Float16* nxt = act_b;
    for (int i = 0; i < 4; ++i) {
      mid_conv<<<dim3(12, 46, nbat), 512, 0, stream>>>(cur, nxt, acc_fc,
                                                       wmid + (size_t)i * 102400, w6s,
                                                       biasmid + i * 64, zbuf, 725, 360, b0);
      _Float16* t = cur; cur = nxt; nxt = t;
    }
    fc_mfma<<<dim3(23, 46, nbat), 256, 0, stream>>>(cur, acc_fc, w6s, zbuf, 725, 360, b0);
  }
  write_desin<<<4079, 256, 0, stream>>>(acc_fc, inputs, b_sin6, out);

  // ---- FBP ----
  ramp_filter<<<1440, 128, 0, stream>>>(out, w_b, f2h);
  backproj<<<1024, 256, 0, stream>>>(at_vals, at_rows, at_cols, f2h, rf);
  write_fbp<<<4096, 256, 0, stream>>>(rf, out + 2092576);

  // ---- image CNN (H=W=512) ----
  hipMemsetAsync(acc_fc, 0, (size_t)262144 * 16, stream);
  for (int p = 0; p < npass; ++p) {
    const int b0 = p * nbat;
    conv1_mfma<1><<<dim3(32, 32, nbat), 256, 0, stream>>>(rf, act_a, w1f + 2048, b_ct1,
                                                          512, 512, b0);
    _Float16* cur = act_a; _Float16* nxt = act_b;
    for (int i = 0; i < 5; ++i) {
      mid_conv<<<dim3(16, 32, nbat), 512, 0, stream>>>(cur, nxt, acc_fc,
                                                       wmid + (size_t)(4 + i) * 102400,
                                                       w6s + 1600,
                                                       biasmid + (4 + i) * 64, zbuf,
                                                       512, 512, b0);
      _Float16* t = cur; cur = nxt; nxt = t;
    }
    fc_mfma<<<dim3(32, 32, nbat), 256, 0, stream>>>(cur, acc_fc, w6s + 1600, zbuf,
                                                    512, 512, b0);
  }
  write_outputs<<<4096, 256, 0, stream>>>(acc_fc, rf, b_ct6, out + 1044000);
}

// Round 8
// 2667.073 us; speedup vs baseline: 1.1896x; 1.1896x over previous
//
#include <hip/hip_runtime.h>
#include <stdint.h>

#define S_DET 725
#define S_ANG 360
#define OUTD  512
#define NB    4

typedef float    float4v __attribute__((ext_vector_type(4)));
typedef int      int4v   __attribute__((ext_vector_type(4)));
typedef _Float16 half8   __attribute__((ext_vector_type(8)));
typedef _Float16 half4   __attribute__((ext_vector_type(4)));
typedef _Float16 half2v  __attribute__((ext_vector_type(2)));

#define GAS __attribute__((address_space(1)))
#define LAS __attribute__((address_space(3)))

// async global->LDS, 16B per lane, LDS dst wave-uniform (lane i writes dst+16*i)
__device__ __forceinline__ void async16(const void* src, void* lds) {
  __builtin_amdgcn_global_load_lds((const GAS void*)(uintptr_t)src,
                                   (LAS void*)(uint32_t)(uintptr_t)lds, 16, 0, 0);
}

// ---------------------------------------------------------------------------
// Weight prep: fold BN into weights/bias, cast f16, transpose to [tap][n][k]
// with 16B-chunk XOR swizzle (chunk g of row n at slot g^(n&7)) — the R4
// layout for LDS double-buffered staging + conflict-free ds_read_b128.
// Tail: w6 [t*64+k] f16; conv1 A-fragments (K=25 taps padded to 32).
// ---------------------------------------------------------------------------
__global__ __launch_bounds__(256)
void prep_weights(const float* __restrict__ wsin, const float* __restrict__ sg,
                  const float* __restrict__ sb,  const float* __restrict__ sm,
                  const float* __restrict__ sv,
                  const float* __restrict__ wct, const float* __restrict__ cg,
                  const float* __restrict__ cbt, const float* __restrict__ cm,
                  const float* __restrict__ cv,
                  const float* __restrict__ wsin6, const float* __restrict__ wct6,
                  const float* __restrict__ wsin1, const float* __restrict__ wct1,
                  _Float16* __restrict__ wout, float* __restrict__ bout,
                  _Float16* __restrict__ w6out, _Float16* __restrict__ w1fout)
{
  int id = blockIdx.x * 256 + threadIdx.x;
  if (id < 9 * 102400) {
    int l   = id / 102400;          // layer 0..8 (0-3 sinogram, 4-8 image)
    int rem = id - l * 102400;      // t*4096 + k*64 + n  (source [5][5][64][64])
    int t = rem >> 12;
    int kn = rem & 4095;
    int k = kn >> 6, n = kn & 63;
    const float *w, *g, *b, *m, *v;
    if (l < 4) { w = wsin + l*102400; g = sg + l*64; b = sb + l*64; m = sm + l*64; v = sv + l*64; }
    else { int li = l - 4; w = wct + li*102400; g = cg + li*64; b = cbt + li*64; m = cm + li*64; v = cv + li*64; }
    float s = g[n] * rsqrtf(v[n] + 1e-3f);
    float val = w[rem] * s;
    int slot = (k >> 3) ^ (n & 7);
    wout[(size_t)l*102400 + t*4096 + n*64 + slot*8 + (k & 7)] = (_Float16)val;
    if (rem < 64)  // t==0,k==0 -> n==rem
      bout[l*64 + rem] = b[rem] - m[rem] * s;
  } else {
    int r = id - 9 * 102400;
    if (r < 3200) {  // [0,1600) sino w6, [1600,3200) ct w6; layout [t*64+k]
      w6out[r] = (_Float16)(r < 1600 ? wsin6[r] : wct6[r - 1600]);
    } else if (r < 3200 + 4096) {
      // conv1 A-fragments: q = layer*2048 + ci*512 + ln*8 + e
      int q = r - 3200;
      int layer = q >> 11;
      int idx = q & 2047;
      int ci = idx >> 9, ln = (idx >> 3) & 63, e = idx & 7;
      int ch = ci * 16 + (ln & 15);
      int k = (ln >> 4) * 8 + e;          // tap index (pad >=25 -> 0)
      float val = 0.f;
      if (k < 25) val = (layer ? wct1 : wsin1)[k * 64 + ch];
      w1fout[q] = (_Float16)val;
    }
  }
}

// ---------------------------------------------------------------------------
// First conv 1->64 via MFMA im2col (R6, proven).
// ---------------------------------------------------------------------------
template <int IMG>
__global__ __launch_bounds__(256)
void conv1_mfma(const float* __restrict__ src, _Float16* __restrict__ dst,
                const _Float16* __restrict__ w1f, const float* __restrict__ b1,
                int H, int W, int b0)
{
  __shared__ __align__(16) float rawt[400];
  __shared__ __align__(16) char imc[256 * 80];
  const int tid = threadIdx.x;
  const int wv = tid >> 6, ln = tid & 63;
  const int bz = blockIdx.z, gb = b0 + bz;
  const int y0 = blockIdx.y * 16, x0 = blockIdx.x * 16;
  for (int i = tid; i < 400; i += 256) {
    int iy = i / 20, ix = i - iy * 20;
    int y = y0 - 2 + iy, x = x0 - 2 + ix;
    float v = 0.f;
    if (y >= 0 && y < H && x >= 0 && x < W) {
      if (IMG) v = 4.f * src[(size_t)(y * W + x) * 4 + gb];
      else     v = src[((size_t)gb * H + y) * W + x];
    }
    rawt[i] = v;
  }
  __syncthreads();
  {
    const int ty = tid >> 4, tx = tid & 15;
    _Float16 row[32];
    int dy = 0, dx = 0;
#pragma unroll
    for (int t = 0; t < 25; ++t) {
      row[t] = (_Float16)rawt[(ty + dy) * 20 + tx + dx];
      if (++dx == 5) { dx = 0; ++dy; }
    }
#pragma unroll
    for (int t = 25; t < 32; ++t) row[t] = (_Float16)0.f;
    char* dp = imc + tid * 80;
#pragma unroll
    for (int j = 0; j < 4; ++j)
      *(half8*)(dp + j * 16) = *(const half8*)((const char*)row + j * 16);
  }
  __syncthreads();

  half8 wf[4];
#pragma unroll
  for (int ci = 0; ci < 4; ++ci) wf[ci] = ((const half8*)w1f)[ci * 64 + ln];

  float4v acc[4][4];
#pragma unroll
  for (int pi = 0; pi < 4; ++pi)
#pragma unroll
    for (int ci = 0; ci < 4; ++ci) acc[pi][ci] = (float4v){0.f, 0.f, 0.f, 0.f};

#pragma unroll
  for (int pi = 0; pi < 4; ++pi) {
    const int px = (wv * 4 + pi) * 16 + (ln & 15);
    half8 af = *(const half8*)(imc + px * 80 + ((ln >> 4) << 4));
#pragma unroll
    for (int ci = 0; ci < 4; ++ci)
      acc[pi][ci] = __builtin_amdgcn_mfma_f32_16x16x32_f16(wf[ci], af, acc[pi][ci], 0, 0, 0);
  }

  const int tx = ln & 15;
  const int x = x0 + tx;
#pragma unroll
  for (int pi = 0; pi < 4; ++pi) {
    const int y = y0 + wv * 4 + pi;
    if (y < H && x < W) {
      _Float16* dp = dst + ((size_t)(bz * H + y) * W + x) * 64;
#pragma unroll
      for (int ci = 0; ci < 4; ++ci) {
        const int cbase = ci * 16 + (ln >> 4) * 4;
        const float4v bv = *(const float4v*)(b1 + cbase);
        half4 h;
#pragma unroll
        for (int r = 0; r < 4; ++r) {
          float v = acc[pi][ci][r] + bv[r];
          v = v > 0.f ? v : 0.f;
          h[r] = (_Float16)v;
        }
        *(half4*)(dp + cbase) = h;
      }
    }
  }
}

// ---------------------------------------------------------------------------
// Residual conv 64->64 + folded-BN bias + relu via MFMA 16x16x32 f16 — the
// R4-proven structure: XOR-swizzled 20x20px atile, LDS double-buffered 8KB
// weight staging (1 barrier/tap, overlapped across 2 blocks/CU), w6 staged
// to LDS once and riding as an extra A-row on the same B pixel frags.
// ---------------------------------------------------------------------------
__global__ __launch_bounds__(256, 2)
void mid_conv(const _Float16* __restrict__ src, _Float16* __restrict__ dst,
              float* __restrict__ accum,
              const _Float16* __restrict__ wt, const _Float16* __restrict__ w6g,
              const float* __restrict__ bias, const char* __restrict__ zbuf,
              int H, int W, int b0)
{
  __shared__ __align__(16) char smem[51200 + 2 * 8192 + 3200 + 16];
  char* const atile = smem;                       // 400 px * 128B
  char* const wbuf  = smem + 51200;               // 2 x 8KB weight dbuf
  _Float16* const w6l = (_Float16*)(smem + 51200 + 16384);  // 25x64 f16
  char* const zl = smem + 51200 + 16384 + 3200;   // 16B zeros
  const int tid = threadIdx.x;
  const int wv = tid >> 6, ln = tid & 63;
  const int bz = blockIdx.z, gb = b0 + bz;
  const int y0 = blockIdx.y * 16, x0 = blockIdx.x * 16;

  if (tid < 200) ((half8*)w6l)[tid] = ((const half8*)w6g)[tid];
  if (tid < 4) ((int*)zl)[tid] = 0;

  // stage input tile: 400 px * 8 chunks = 50 wave-instructions
  for (int inst = wv; inst < 50; inst += 4) {
    const int slot = inst * 64 + ln;
    const int p = slot >> 3, gp = slot & 7;
    const int g = gp ^ (p & 7);
    const int iy = p / 20, ix = p - iy * 20;
    const int y = y0 - 2 + iy, x = x0 - 2 + ix;
    const char* sp = (y >= 0 && y < H && x >= 0 && x < W)
        ? (const char*)(src + ((size_t)(bz * H + y) * W + x) * 64) + g * 16
        : zbuf + g * 16;
    async16(sp, atile + inst * 1024);
  }
  // tap-0 weights into buffer 0
#pragma unroll
  for (int j = 0; j < 2; ++j) {
    const int inst = wv * 2 + j;
    async16((const char*)wt + inst * 1024 + ln * 16, wbuf + inst * 1024);
  }
  __syncthreads();

  float4v acc[4][4];
  float4v acc6[4];
#pragma unroll
  for (int pi = 0; pi < 4; ++pi) {
    acc6[pi] = (float4v){0.f, 0.f, 0.f, 0.f};
#pragma unroll
    for (int ci = 0; ci < 4; ++ci) acc[pi][ci] = (float4v){0.f, 0.f, 0.f, 0.f};
  }

  int dy = 0, dx = 0;
  for (int t = 0; t < 25; ++t) {
    if (t < 24) {  // prefetch next tap's weights into the other buffer
      char* wdst = wbuf + ((t + 1) & 1) * 8192;
#pragma unroll
      for (int j = 0; j < 2; ++j) {
        const int inst = wv * 2 + j;
        async16((const char*)wt + (t + 1) * 8192 + inst * 1024 + ln * 16,
                wdst + inst * 1024);
      }
    }
    const char* wb = wbuf + (t & 1) * 8192;
#pragma unroll
    for (int kc = 0; kc < 2; ++kc) {
      const int g0 = kc * 4 + (ln >> 4);
      half8 wf[4], af[4], wf6;
#pragma unroll
      for (int ci = 0; ci < 4; ++ci) {
        const int ch = ci * 16 + (ln & 15);
        wf[ci] = *(const half8*)(wb + ch * 128 + ((g0 ^ (ch & 7)) << 4));
      }
      wf6 = *(const half8*)((ln & 15) == 0
                ? (const char*)(w6l + t * 64 + kc * 32 + ((ln >> 4) << 3))
                : zl);
#pragma unroll
      for (int pi = 0; pi < 4; ++pi) {
        const int p = (wv * 4 + pi + dy) * 20 + (ln & 15) + dx;
        af[pi] = *(const half8*)(atile + p * 128 + ((g0 ^ (p & 7)) << 4));
      }
#pragma unroll
      for (int pi = 0; pi < 4; ++pi) {
#pragma unroll
        for (int ci = 0; ci < 4; ++ci)
          acc[pi][ci] = __builtin_amdgcn_mfma_f32_16x16x32_f16(
              wf[ci], af[pi], acc[pi][ci], 0, 0, 0);
        acc6[pi] = __builtin_amdgcn_mfma_f32_16x16x32_f16(
            wf6, af[pi], acc6[pi], 0, 0, 0);
      }
    }
    if (++dx == 5) { dx = 0; ++dy; }
    __syncthreads();
  }

  // epilogue: D[m=ch][n=px]; lane holds 4 consecutive channels of 1 pixel
  const int tx = ln & 15;
  const int x = x0 + tx;
#pragma unroll
  for (int pi = 0; pi < 4; ++pi) {
    const int y = y0 + wv * 4 + pi;
    if (y < H && x < W) {
      _Float16* dp = dst + ((size_t)(bz * H + y) * W + x) * 64;
#pragma unroll
      for (int ci = 0; ci < 4; ++ci) {
        const int cbase = ci * 16 + (ln >> 4) * 4;
        const float4v bv = *(const float4v*)(bias + cbase);
        half4 h;
#pragma unroll
        for (int r = 0; r < 4; ++r) {
          float v = acc[pi][ci][r] + bv[r];
          v = v > 0.f ? v : 0.f;
          h[r] = (_Float16)v;
        }
        *(half4*)(dp + cbase) = h;
      }
    }
  }
  // fused fc of the input map: D row m=0 lives in lanes 0..15, reg 0
  if (ln < 16) {
#pragma unroll
    for (int pi = 0; pi < 4; ++pi) {
      const int y = y0 + wv * 4 + pi, x2 = x0 + ln;
      if (y < H && x2 < W)
        accum[((size_t)gb * H + y) * W + x2] += acc6[pi][0];
    }
  }
}

// ---------------------------------------------------------------------------
// 64->1 conv of the LAST activation map (R6, proven).
// ---------------------------------------------------------------------------
__global__ __launch_bounds__(256, 3)
void fc_mfma(const _Float16* __restrict__ src, float* __restrict__ accum,
             const _Float16* __restrict__ w6g, const char* __restrict__ zbuf,
             int H, int W, int b0)
{
  __shared__ __align__(16) char atile[51200];
  const int tid = threadIdx.x;
  const int wv = tid >> 6, ln = tid & 63;
  const int bz = blockIdx.z, gb = b0 + bz;
  const int y0 = blockIdx.y * 16, x0 = blockIdx.x * 16;
  for (int inst = wv; inst < 50; inst += 4) {
    const int slot = inst * 64 + ln;
    const int p = slot >> 3, gp = slot & 7;
    const int g = gp ^ (p & 7);
    const int iy = p / 20, ix = p - iy * 20;
    const int y = y0 - 2 + iy, x = x0 - 2 + ix;
    const char* sp = (y >= 0 && y < H && x >= 0 && x < W)
        ? (const char*)(src + ((size_t)(bz * H + y) * W + x) * 64) + g * 16
        : zbuf + g * 16;
    async16(sp, atile + inst * 1024);
  }
  __syncthreads();

  float4v acc6[4];
#pragma unroll
  for (int pi = 0; pi < 4; ++pi) acc6[pi] = (float4v){0.f, 0.f, 0.f, 0.f};

  int dy = 0, dx = 0;
  for (int t = 0; t < 25; ++t) {
#pragma unroll
    for (int kc = 0; kc < 2; ++kc) {
      const int g0 = kc * 4 + (ln >> 4);
      half8 wf6 = {(_Float16)0, (_Float16)0, (_Float16)0, (_Float16)0,
                   (_Float16)0, (_Float16)0, (_Float16)0, (_Float16)0};
      if ((ln & 15) == 0)
        wf6 = *(const half8*)(w6g + t * 64 + kc * 32 + ((ln >> 4) << 3));
#pragma unroll
      for (int pi = 0; pi < 4; ++pi) {
        const int p = (wv * 4 + pi + dy) * 20 + (ln & 15) + dx;
        half8 af = *(const half8*)(atile + p * 128 + ((g0 ^ (p & 7)) << 4));
        acc6[pi] = __builtin_amdgcn_mfma_f32_16x16x32_f16(wf6, af, acc6[pi], 0, 0, 0);
      }
    }
    if (++dx == 5) { dx = 0; ++dy; }
  }
  if (ln < 16) {
#pragma unroll
    for (int pi = 0; pi < 4; ++pi) {
      const int y = y0 + wv * 4 + pi, x2 = x0 + ln;
      if (y < H && x2 < W)
        accum[((size_t)gb * H + y) * W + x2] += acc6[pi][0];
    }
  }
}

// ---------------------------------------------------------------------------
__global__ __launch_bounds__(256)
void write_desin(const float* __restrict__ accf, const float* __restrict__ inputs,
                 const float* __restrict__ b6, float* __restrict__ out)
{
  int id = blockIdx.x * 256 + threadIdx.x;
  if (id < NB * S_DET * S_ANG) out[id] = accf[id] * 0.25f + b6[0] + inputs[id];
}

// ---------------------------------------------------------------------------
__global__ __launch_bounds__(128)
void ramp_filter(const float* __restrict__ desin, const float* __restrict__ wb,
                 _Float16* __restrict__ f2h)
{
  __shared__ float col[1472];   // zero-padded: data at [368, 368+725)
  __shared__ float wl[725];
  const int blk = blockIdx.x;
  const int b = blk / 360, a = blk - b * 360;
  const int tid = threadIdx.x;
  for (int i = tid; i < 1472; i += 128) col[i] = 0.f;
  for (int i = tid; i < 725; i += 128) wl[i] = wb[i];
  __syncthreads();
  for (int i = tid; i < 725; i += 128) col[368 + i] = desin[(b * 725 + i) * 360 + a];
  __syncthreads();
  const int s0 = tid * 6;
  if (s0 < 725) {
    float o0 = 0, o1 = 0, o2 = 0, o3 = 0, o4 = 0, o5 = 0;
    const float* cb = col + 6 + s0;  // cb[t+j] = x[s0+j + t - 362]
    float r0 = cb[0], r1 = cb[1], r2 = cb[2], r3 = cb[3], r4 = cb[4], r5 = cb[5];
    for (int t = 0; t < 725; ++t) {
      float w = wl[t];
      o0 += r0 * w; o1 += r1 * w; o2 += r2 * w;
      o3 += r3 * w; o4 += r4 * w; o5 += r5 * w;
      r0 = r1; r1 = r2; r2 = r3; r3 = r4; r4 = r5; r5 = cb[t + 6];
    }
    float o[6] = { o0, o1, o2, o3, o4, o5 };
#pragma unroll
    for (int j = 0; j < 6; ++j)
      if (s0 + j < 725) f2h[((size_t)a * 725 + s0 + j) * 4 + b] = (_Float16)o[j];
  }
}

// ---------------------------------------------------------------------------
// Sparse backprojection: 32 nnz/thread, boundary atomics + interior plain
// stores, NT loads on the streams.
// ---------------------------------------------------------------------------
__global__ __launch_bounds__(256)
void backproj(const float* __restrict__ vals, const int* __restrict__ rows,
              const int* __restrict__ cols, const _Float16* __restrict__ f2h,
              float* __restrict__ rf)
{
  const int tid = blockIdx.x * 256 + threadIdx.x;   // 262144 threads
  const size_t i0 = (size_t)tid * 32;
  const int4v* rp = (const int4v*)(rows + i0);
  const int4v* cp = (const int4v*)(cols + i0);
  const float4v* vp = (const float4v*)(vals + i0);
  float a0 = 0, a1 = 0, a2 = 0, a3 = 0;
  int4v r0v = __builtin_nontemporal_load(rp);
  int cur = r0v[0];
  bool first = true;
#pragma unroll 4
  for (int q = 0; q < 8; ++q) {
    int4v r4 = (q == 0) ? r0v : __builtin_nontemporal_load(rp + q);
    int4v c4 = __builtin_nontemporal_load(cp + q);
    float4v v4 = __builtin_nontemporal_load(vp + q);
#pragma unroll
    for (int u = 0; u < 4; ++u) {
      int r = r4[u]; int c = c4[u]; float v = v4[u];
      if (r != cur) {
        float* p = rf + (size_t)cur * 4;
        if (first) {
          atomicAdd(p + 0, a0); atomicAdd(p + 1, a1);
          atomicAdd(p + 2, a2); atomicAdd(p + 3, a3);
          first = false;
        } else {
          p[0] = a0; p[1] = a1; p[2] = a2; p[3] = a3;
        }
        a0 = a1 = a2 = a3 = 0; cur = r;
      }
      const half4 f = *(const half4*)(f2h + (size_t)c * 4);
      a0 += v * (float)f[0]; a1 += v * (float)f[1];
      a2 += v * (float)f[2]; a3 += v * (float)f[3];
    }
  }
  float* p = rf + (size_t)cur * 4;
  atomicAdd(p + 0, a0); atomicAdd(p + 1, a1);
  atomicAdd(p + 2, a2); atomicAdd(p + 3, a3);
}

__global__ __launch_bounds__(256)
void write_fbp(const float* __restrict__ rf, float* __restrict__ out)
{
  int id = blockIdx.x * 256 + threadIdx.x;  // 4*262144 exact
  int b = id >> 18, p = id & 262143;
  out[id] = 4.f * rf[(size_t)p * 4 + b];
}

__global__ __launch_bounds__(256)
void write_outputs(const float* __restrict__ accf, const float* __restrict__ rf,
                   const float* __restrict__ b6, float* __restrict__ out)
{
  int id = blockIdx.x * 256 + threadIdx.x;  // 4*262144 exact
  int b = id >> 18, p = id & 262143;
  out[id] = accf[id] * 0.2f + b6[0] + 4.f * rf[(size_t)p * 4 + b];
}

// ---------------------------------------------------------------------------
extern "C" void kernel_launch(void* const* d_in, const int* in_sizes, int n_in,
                              void* d_out, int out_size, void* d_ws, size_t ws_size,
                              hipStream_t stream)
{
  (void)in_sizes; (void)n_in; (void)out_size;
  const float* inputs   = (const float*)d_in[0];
  const float* w_sin1   = (const float*)d_in[1];
  const float* b_sin1   = (const float*)d_in[2];
  const float* w_sin_mid= (const float*)d_in[3];
  const float* sin_gamma= (const float*)d_in[4];
  const float* sin_beta = (const float*)d_in[5];
  const float* sin_mean = (const float*)d_in[6];
  const float* sin_var  = (const float*)d_in[7];
  const float* w_sin6   = (const float*)d_in[8];
  const float* b_sin6   = (const float*)d_in[9];
  const float* w_ct1    = (const float*)d_in[10];
  const float* b_ct1    = (const float*)d_in[11];
  const float* w_ct_mid = (const float*)d_in[12];
  const float* ct_gamma = (const float*)d_in[13];
  const float* ct_beta  = (const float*)d_in[14];
  const float* ct_mean  = (const float*)d_in[15];
  const float* ct_var   = (const float*)d_in[16];
  const float* w_ct6    = (const float*)d_in[17];
  const float* b_ct6    = (const float*)d_in[18];
  const float* w_b      = (const float*)d_in[19];
  const float* at_vals  = (const float*)d_in[20];
  const int*   at_rows  = (const int*)d_in[21];
  const int*   at_cols  = (const int*)d_in[22];
  float* out = (float*)d_out;

  // adaptive batching: fixed tables ~11 MB; activations 2 x nbat x 33.55 MB.
  const size_t base = (size_t)11 << 20;
  const size_t act_per_batch = (size_t)2 * 262144 * 128;  // both ping-pong bufs
  int nbat = 1;
  if (ws_size >= base + 4 * act_per_batch) nbat = 4;
  else if (ws_size >= base + 2 * act_per_batch) nbat = 2;
  const int npass = 4 / nbat;

  char* ws = (char*)d_ws;
  size_t off = 0;
  auto alloc = [&](size_t bytes) {
    char* p = ws + off;
    off = (off + bytes + 255) & ~(size_t)255;
    return p;
  };
  char*     zbuf    = alloc(256);
  _Float16* wmid    = (_Float16*)alloc((size_t)9 * 102400 * 2);
  float*    biasmid = (float*)alloc(9 * 64 * 4);
  _Float16* w6s     = (_Float16*)alloc(3200 * 2);
  _Float16* w1f     = (_Float16*)alloc(4096 * 2);
  float*    rf      = (float*)alloc((size_t)262144 * 16);
  char*     shreg   = alloc((size_t)262144 * 16);  // f2h (2.1MB) / acc_fc (4.18MB) union
  _Float16* act_a   = (_Float16*)alloc((size_t)nbat * 262144 * 128);
  _Float16* act_b   = (_Float16*)alloc((size_t)nbat * 262144 * 128);
  _Float16* f2h    = (_Float16*)shreg;
  float*    acc_fc = (float*)shreg;

  hipMemsetAsync(zbuf, 0, 256, stream);
  hipMemsetAsync(rf, 0, (size_t)262144 * 16, stream);
  hipMemsetAsync(acc_fc, 0, (size_t)262144 * 16, stream);

  prep_weights<<<3630, 256, 0, stream>>>(w_sin_mid, sin_gamma, sin_beta, sin_mean, sin_var,
                                         w_ct_mid, ct_gamma, ct_beta, ct_mean, ct_var,
                                         w_sin6, w_ct6, w_sin1, w_ct1,
                                         wmid, biasmid, w6s, w1f);

  // ---- sinogram CNN (H=725, W=360) ----
  for (int p = 0; p < npass; ++p) {
    const int b0 = p * nbat;
    conv1_mfma<0><<<dim3(23, 46, nbat), 256, 0, stream>>>(inputs, act_a, w1f, b_sin1,
                                                          725, 360, b0);
    _Float16* cur = act_a; _Float16* nxt = act_b;
    for (int i = 0; i < 4; ++i) {
      mid_conv<<<dim3(23, 46, nbat), 256, 0, stream>>>(cur, nxt, acc_fc,
                                                       wmid + (size_t)i * 102400, w6s,
                                                       biasmid + i * 64, zbuf, 725, 360, b0);
      _Float16* t = cur; cur = nxt; nxt = t;
    }
    fc_mfma<<<dim3(23, 46, nbat), 256, 0, stream>>>(cur, acc_fc, w6s, zbuf, 725, 360, b0);
  }
  write_desin<<<4079, 256, 0, stream>>>(acc_fc, inputs, b_sin6, out);

  // ---- FBP ----
  ramp_filter<<<1440, 128, 0, stream>>>(out, w_b, f2h);
  backproj<<<1024, 256, 0, stream>>>(at_vals, at_rows, at_cols, f2h, rf);
  write_fbp<<<4096, 256, 0, stream>>>(rf, out + 2092576);

  // ---- image CNN (H=W=512) ----
  hipMemsetAsync(acc_fc, 0, (size_t)262144 * 16, stream);
  for (int p = 0; p < npass; ++p) {
    const int b0 = p * nbat;
    conv1_mfma<1><<<dim3(32, 32, nbat), 256, 0, stream>>>(rf, act_a, w1f + 2048, b_ct1,
                                                          512, 512, b0);
    _Float16* cur = act_a; _Float16* nxt = act_b;
    for (int i = 0; i < 5; ++i) {
      mid_conv<<<dim3(32, 32, nbat), 256, 0, stream>>>(cur, nxt, acc_fc,
                                                       wmid + (size_t)(4 + i) * 102400,
                                                       w6s + 1600,
                                                       biasmid + (4 + i) * 64, zbuf,
                                                       512, 512, b0);
      _Float16* t = cur; cur = nxt; nxt = t;
    }
    fc_mfma<<<dim3(32, 32, nbat), 256, 0, stream>>>(cur, acc_fc, w6s + 1600, zbuf,
                                                    512, 512, b0);
  }
  write_outputs<<<4096, 256, 0, stream>>>(acc_fc, rf, b_ct6, out + 1044000);
}